// Round 2
// baseline (431.672 us; speedup 1.0000x reference)
//
#include <hip/hip_runtime.h>
#include <hip/hip_bf16.h>

#define HH 128          // hidden size H
#define ROWS 64         // edge rows per GEMM block
#define BLK 256         // threads per GEMM block
#define NB 128          // batches
#define NN 64           // nodes per batch

static inline int cdiv(int a, int b) { return (a + b - 1) / b; }

__device__ __forceinline__ float tanh_fast(float x) {
    float ax = fabsf(x);
    float ex = __expf(-2.0f * ax);
    float t  = (1.0f - ex) / (1.0f + ex);
    return copysignf(t, x);
}

__device__ __forceinline__ float4 tanh4(float4 v) {
    return make_float4(tanh_fast(v.x), tanh_fast(v.y), tanh_fast(v.z), tanh_fast(v.w));
}

// idmat[(b*64+n)*64+nhb] = e  (edge id scatter; every rev-slot we later read exists
// because A is symmetric)
__global__ void scatter_ids_kernel(const int* __restrict__ bI, const int* __restrict__ nI,
                                   const int* __restrict__ nhI, int* __restrict__ idmat, int E) {
    int e = blockIdx.x * blockDim.x + threadIdx.x;
    if (e >= E) return;
    idmat[((bI[e] << 6) + nI[e]) * NN + nhI[e]] = e;
}

__global__ void build_rev_kernel(const int* __restrict__ bI, const int* __restrict__ nI,
                                 const int* __restrict__ nhI, const int* __restrict__ idmat,
                                 int* __restrict__ rev, int E) {
    int e = blockIdx.x * blockDim.x + threadIdx.x;
    if (e >= E) return;
    rev[e] = idmat[((bI[e] << 6) + nhI[e]) * NN + nI[e]];
}

// node_ptr[v] = lower_bound over edges of seg(e)=b*64+n (edges emitted by np.nonzero
// in sorted (b,n,nhb) order, so each node's out-edges are one contiguous run)
__global__ void build_ptr_kernel(const int* __restrict__ bI, const int* __restrict__ nI,
                                 int E, int* __restrict__ ptr) {
    int v = blockIdx.x * blockDim.x + threadIdx.x;
    if (v > NB * NN) return;
    int lo = 0, hi = E;
    while (lo < hi) {
        int mid = (lo + hi) >> 1;
        int sg = (bI[mid] << 6) + nI[mid];
        if (sg < v) lo = mid + 1; else hi = mid;
    }
    ptr[v] = lo;
}

// S[v][h] = sum over edges with source-node v of mem[e][h]   (contiguous segment)
__global__ void node_sum_kernel(const float* __restrict__ mem, const int* __restrict__ ptr,
                                float* __restrict__ S) {
    int v = blockIdx.x;
    int h = threadIdx.x;
    int s = ptr[v], e1 = ptr[v + 1];
    float acc = 0.f;
    for (int e = s; e < e1; ++e) acc += mem[(size_t)e * HH + h];
    S[(size_t)v * HH + h] = acc;
}

// MODE 0: t = tanh(cat @ W_emb + b_emb)                  (K=144) -> out0
// MODE 1: ef2 = t @ W_edge + b_prop; mem1 = tanh(ef2)    (K=128) -> out0=ef2, out1=mem1
// MODE 2: mem' = tanh((S[nhb]-mem[rev]) @ W_msg + ef2)   (K=128) -> out0
// Column ownership per thread: cols {tc*4..+3} and {tc*4+64..+67} -> WLDS reads are
// 2-way bank aliased (free, m136) instead of the 4-way of a tc*8 mapping.
template <int MODE>
__global__ __launch_bounds__(BLK) void gemm_kernel(
    const float* __restrict__ nodes, const float* __restrict__ edgesF,
    const float* __restrict__ tIn, const float* __restrict__ S,
    const float* __restrict__ memIn, const int* __restrict__ rev,
    const float* __restrict__ W, const float* __restrict__ bias,
    const float* __restrict__ ef2in,
    float* __restrict__ out0, float* __restrict__ out1,
    const int* __restrict__ bI, const int* __restrict__ nI, const int* __restrict__ nhI,
    int E)
{
    constexpr int K   = (MODE == 0) ? 144 : 128;
    constexpr int KC  = (MODE == 0) ? 48  : 32;   // K % KC == 0 in both cases
    constexpr int LDI = K + 4;                    // +4 floats: rows 4 apart -> 2-way (free)
    __shared__ __align__(16) float inLDS[ROWS][LDI];
    __shared__ __align__(16) float WLDS[KC][HH + 4];

    const int tid = threadIdx.x;
    const int e0  = blockIdx.x * ROWS;

    // ---- stage input rows (full K) into LDS ----
    constexpr int F4R = K / 4;
    for (int slot = tid; slot < ROWS * F4R; slot += BLK) {
        int r  = slot / F4R;
        int k0 = (slot % F4R) * 4;
        int e  = e0 + r;
        float4 v = make_float4(0.f, 0.f, 0.f, 0.f);
        if (e < E) {
            if (MODE == 0) {
                int b = bI[e], n = nI[e], nh = nhI[e];
                if (k0 < 64)
                    v = *(const float4*)&nodes[(((b << 6) + n) << 6) + k0];
                else if (k0 < 128)
                    v = *(const float4*)&nodes[(((b << 6) + nh) << 6) + (k0 - 64)];
                else
                    v = *(const float4*)&edgesF[(((((b << 6) + n) << 6) + nh) << 4) + (k0 - 128)];
            } else if (MODE == 1) {
                v = *(const float4*)&tIn[(size_t)e * HH + k0];
            } else {
                int b = bI[e], nh = nhI[e];
                float4 sv = *(const float4*)&S[(size_t)((b << 6) + nh) * HH + k0];
                float4 mv = *(const float4*)&memIn[(size_t)rev[e] * HH + k0];
                v = make_float4(sv.x - mv.x, sv.y - mv.y, sv.z - mv.z, sv.w - mv.w);
            }
        }
        *(float4*)&inLDS[r][k0] = v;
    }

    const int tc = tid & 15, tr = tid >> 4;
    const int c0 = tc * 4, r0 = tr * 4;
    float acc[4][8];    // [row i][0..3 -> col c0+j, 4..7 -> col c0+64+j]
    #pragma unroll
    for (int i = 0; i < 4; ++i)
        #pragma unroll
        for (int c = 0; c < 8; ++c) acc[i][c] = 0.f;

    // ---- K loop, W chunked KC rows at a time through LDS ----
    for (int kc = 0; kc < K; kc += KC) {
        __syncthreads();   // prev chunk's compute done (first iter: input staged)
        constexpr int WSLOTS = KC * (HH / 4);
        #pragma unroll
        for (int ii = 0; ii < WSLOTS / BLK; ++ii) {
            int sl = tid + ii * BLK;
            int kl = sl >> 5;
            int cq = (sl & 31) * 4;
            *(float4*)&WLDS[kl][cq] = *(const float4*)&W[(size_t)(kc + kl) * HH + cq];
        }
        __syncthreads();
        #pragma unroll
        for (int kk = 0; kk < KC; kk += 4) {
            float4 a[4];
            #pragma unroll
            for (int i = 0; i < 4; ++i) a[i] = *(const float4*)&inLDS[r0 + i][kc + kk];
            #pragma unroll
            for (int j = 0; j < 4; ++j) {
                float4 w0 = *(const float4*)&WLDS[kk + j][c0];
                float4 w1 = *(const float4*)&WLDS[kk + j][c0 + 64];
                #pragma unroll
                for (int i = 0; i < 4; ++i) {
                    float s = (j == 0) ? a[i].x : (j == 1) ? a[i].y : (j == 2) ? a[i].z : a[i].w;
                    acc[i][0] += s * w0.x; acc[i][1] += s * w0.y;
                    acc[i][2] += s * w0.z; acc[i][3] += s * w0.w;
                    acc[i][4] += s * w1.x; acc[i][5] += s * w1.y;
                    acc[i][6] += s * w1.z; acc[i][7] += s * w1.w;
                }
            }
        }
    }

    // ---- epilogue (vectorized float4) ----
    #pragma unroll
    for (int i = 0; i < 4; ++i) {
        int e = e0 + r0 + i;
        if (e >= E) continue;
        float4 v0 = make_float4(acc[i][0], acc[i][1], acc[i][2], acc[i][3]);
        float4 v1 = make_float4(acc[i][4], acc[i][5], acc[i][6], acc[i][7]);
        size_t base = (size_t)e * HH;
        if (MODE == 0) {
            float4 bb0 = *(const float4*)&bias[c0];
            float4 bb1 = *(const float4*)&bias[c0 + 64];
            v0.x += bb0.x; v0.y += bb0.y; v0.z += bb0.z; v0.w += bb0.w;
            v1.x += bb1.x; v1.y += bb1.y; v1.z += bb1.z; v1.w += bb1.w;
            *(float4*)&out0[base + c0]      = tanh4(v0);
            *(float4*)&out0[base + c0 + 64] = tanh4(v1);
        } else if (MODE == 1) {
            float4 bb0 = *(const float4*)&bias[c0];
            float4 bb1 = *(const float4*)&bias[c0 + 64];
            v0.x += bb0.x; v0.y += bb0.y; v0.z += bb0.z; v0.w += bb0.w;
            v1.x += bb1.x; v1.y += bb1.y; v1.z += bb1.z; v1.w += bb1.w;
            *(float4*)&out0[base + c0]      = v0;          // ef2 (bias folded in)
            *(float4*)&out0[base + c0 + 64] = v1;
            *(float4*)&out1[base + c0]      = tanh4(v0);   // mem after MP iteration 1
            *(float4*)&out1[base + c0 + 64] = tanh4(v1);
        } else {
            float4 f0 = *(const float4*)&ef2in[base + c0];
            float4 f1 = *(const float4*)&ef2in[base + c0 + 64];
            v0.x += f0.x; v0.y += f0.y; v0.z += f0.z; v0.w += f0.w;
            v1.x += f1.x; v1.y += f1.y; v1.z += f1.z; v1.w += f1.w;
            *(float4*)&out0[base + c0]      = tanh4(v0);
            *(float4*)&out0[base + c0 + 64] = tanh4(v1);
        }
    }
}

// per-batch readout: g[b] = sum of mem over batch's edges; out = g @ W_out + b_out
// (node_mask is redundant: deg==0 nodes contribute zero edges)
__global__ __launch_bounds__(512) void out_kernel(const float* __restrict__ mem,
                                                  const int* __restrict__ ptr,
                                                  const float* __restrict__ W_out,
                                                  const float* __restrict__ b_out,
                                                  float* __restrict__ out) {
    int b   = blockIdx.x;
    int tid = threadIdx.x;
    int sub = tid >> 7, h = tid & 127;
    int s = ptr[b * NN], e1 = ptr[b * NN + NN];
    int len = e1 - s;
    int chunk = (len + 3) >> 2;
    int cs = s + sub * chunk;
    int ce = min(cs + chunk, e1);
    float acc = 0.f;
    for (int e = cs; e < ce; ++e) acc += mem[(size_t)e * HH + h];
    __shared__ float gp[4][128];
    gp[sub][h] = acc;
    __syncthreads();
    if (tid < 128) gp[0][tid] = gp[0][tid] + gp[1][tid] + gp[2][tid] + gp[3][tid];
    __syncthreads();
    if (tid < 32) {
        float a = b_out[tid];
        for (int h2 = 0; h2 < 128; ++h2) a += gp[0][h2] * W_out[h2 * 32 + tid];
        out[b * 32 + tid] = a;
    }
}

extern "C" void kernel_launch(void* const* d_in, const int* in_sizes, int n_in,
                              void* d_out, int out_size, void* d_ws, size_t ws_size,
                              hipStream_t stream) {
    const float* nodes  = (const float*)d_in[0];
    const float* edgesF = (const float*)d_in[1];
    const float* W_emb  = (const float*)d_in[2];
    const float* b_emb  = (const float*)d_in[3];
    const float* W_msg  = (const float*)d_in[4];
    const float* W_edge = (const float*)d_in[5];
    const float* b_prop = (const float*)d_in[6];
    const float* W_out  = (const float*)d_in[7];
    const float* b_out  = (const float*)d_in[8];
    const int*   bI     = (const int*)d_in[9];
    const int*   nI     = (const int*)d_in[10];
    const int*   nhI    = (const int*)d_in[11];
    const int    E      = in_sizes[9];
    float*       out    = (float*)d_out;

    // workspace carve-up (all 256B-aligned)
    char* ws = (char*)d_ws;
    size_t szEH = (((size_t)E * HH * sizeof(float)) + 255) & ~(size_t)255;
    float* ef2  = (float*)ws;
    float* memA = (float*)(ws + szEH);
    float* memB = (float*)(ws + 2 * szEH);       // also holds t between stage A and B
    float* S    = (float*)(ws + 3 * szEH);
    size_t szS  = (size_t)NB * NN * HH * sizeof(float);          // 4 MB
    int* idmat  = (int*)(ws + 3 * szEH + szS);
    size_t szId = (size_t)NB * NN * NN * sizeof(int);            // 2 MB
    int* rev    = (int*)(ws + 3 * szEH + szS + szId);
    size_t szRv = (((size_t)E * sizeof(int)) + 255) & ~(size_t)255;
    int* ptr    = (int*)(ws + 3 * szEH + szS + szId + szRv);

    // graph index prep
    scatter_ids_kernel<<<cdiv(E, 256), 256, 0, stream>>>(bI, nI, nhI, idmat, E);
    build_rev_kernel<<<cdiv(E, 256), 256, 0, stream>>>(bI, nI, nhI, idmat, rev, E);
    build_ptr_kernel<<<cdiv(NB * NN + 1, 256), 256, 0, stream>>>(bI, nI, E, ptr);

    const int gblocks = cdiv(E, ROWS);
    // stage A: t = tanh(cat @ W_emb + b_emb)  (t stored in memB region)
    gemm_kernel<0><<<gblocks, BLK, 0, stream>>>(nodes, edgesF, nullptr, nullptr, nullptr, nullptr,
                                                W_emb, b_emb, nullptr, memB, nullptr,
                                                bI, nI, nhI, E);
    // stage B: ef2 = t @ W_edge + b_prop ; memA = tanh(ef2)   (MP iteration 1, mem0 == 0)
    gemm_kernel<1><<<gblocks, BLK, 0, stream>>>(nullptr, nullptr, memB, nullptr, nullptr, nullptr,
                                                W_edge, b_prop, nullptr, ef2, memA,
                                                bI, nI, nhI, E);
    // iterations 2..4: msg[e] = S[b,nhb] - mem[rev[e]];  mem' = tanh(msg @ W_msg + ef2)
    const float* mi = memA;
    float*       mo = memB;
    for (int it = 0; it < 3; ++it) {
        node_sum_kernel<<<NB * NN, HH, 0, stream>>>(mi, ptr, S);
        gemm_kernel<2><<<gblocks, BLK, 0, stream>>>(nullptr, nullptr, nullptr, S, mi, rev,
                                                    W_msg, nullptr, ef2, mo, nullptr,
                                                    bI, nI, nhI, E);
        float* tmp = (float*)mi; mi = mo; mo = tmp;
    }
    // after 3 swaps: final mem is in mi (== memB)
    out_kernel<<<NB, 512, 0, stream>>>(mi, ptr, W_out, b_out, out);
}

// Round 3
// 342.441 us; speedup vs baseline: 1.2606x; 1.2606x over previous
//
#include <hip/hip_runtime.h>
#include <hip/hip_bf16.h>

#define NB 128
#define NN 64
#define HH 128

typedef short bf16x8 __attribute__((ext_vector_type(8)));
typedef float f32x4 __attribute__((ext_vector_type(4)));

static inline int cdiv(int a, int b) { return (a + b - 1) / b; }

__device__ __forceinline__ float tanh_fast(float x) {
    float ax = fabsf(x);
    float ex = __expf(-2.0f * ax);
    float t  = (1.0f - ex) / (1.0f + ex);
    return copysignf(t, x);
}

// RNE float->bf16 (raw ushort) and back
__device__ __forceinline__ unsigned short f2bfs(float f) {
    unsigned u; __builtin_memcpy(&u, &f, 4);
    u = (u + 0x7FFFu + ((u >> 16) & 1u)) >> 16;
    return (unsigned short)u;
}
__device__ __forceinline__ float bfs2f(unsigned short s) {
    unsigned u = ((unsigned)s) << 16;
    float f; __builtin_memcpy(&f, &u, 4);
    return f;
}
__device__ __forceinline__ int pack2(unsigned short a, unsigned short b) {
    return (int)((unsigned)a | ((unsigned)b << 16));
}
__device__ __forceinline__ f32x4 mfma16(bf16x8 a, bf16x8 b, f32x4 c) {
    return __builtin_amdgcn_mfma_f32_16x16x32_bf16(a, b, c, 0, 0, 0);
}

// ---------- graph index prep ----------
__global__ void scatter_ids_kernel(const int* __restrict__ bI, const int* __restrict__ nI,
                                   const int* __restrict__ nhI, int* __restrict__ idmat, int E) {
    int e = blockIdx.x * blockDim.x + threadIdx.x;
    if (e >= E) return;
    idmat[((bI[e] << 6) + nI[e]) * NN + nhI[e]] = e;
}
// rev[e] = id of reverse edge (exists: A symmetric); segnh[e] = b*64+nhb (S row / batch id)
__global__ void build_rev_seg_kernel(const int* __restrict__ bI, const int* __restrict__ nI,
                                     const int* __restrict__ nhI, const int* __restrict__ idmat,
                                     int* __restrict__ rev, int* __restrict__ segnh, int E) {
    int e = blockIdx.x * blockDim.x + threadIdx.x;
    if (e >= E) return;
    int b = bI[e], n = nI[e], nh = nhI[e];
    rev[e]   = idmat[((b << 6) + nh) * NN + n];
    segnh[e] = (b << 6) + nh;
}
// node_ptr[v] = lower_bound of seg(e)=b*64+n (edges sorted by (b,n,nhb))
__global__ void build_ptr_kernel(const int* __restrict__ bI, const int* __restrict__ nI,
                                 int E, int* __restrict__ ptr) {
    int v = blockIdx.x * blockDim.x + threadIdx.x;
    if (v > NB * NN) return;
    int lo = 0, hi = E;
    while (lo < hi) {
        int mid = (lo + hi) >> 1;
        int sg = (bI[mid] << 6) + nI[mid];
        if (sg < v) lo = mid + 1; else hi = mid;
    }
    ptr[v] = lo;
}
// transpose weights to bf16 WT[col][k]; K of W_emb zero-padded 144->160; zero g
__global__ void prep_w_kernel(const float* __restrict__ W_emb, const float* __restrict__ W_edge,
                              const float* __restrict__ W_msg,
                              unsigned short* __restrict__ WTe, unsigned short* __restrict__ WTd,
                              unsigned short* __restrict__ WTm, float* __restrict__ g) {
    int i = blockIdx.x * blockDim.x + threadIdx.x;
    if (i < 128 * 160) { int c = i / 160, k = i % 160;
        WTe[c * 160 + k] = f2bfs(k < 144 ? W_emb[k * 128 + c] : 0.f); return; }
    i -= 128 * 160;
    if (i < 128 * 128) { int c = i >> 7, k = i & 127;
        WTd[c * 128 + k] = f2bfs(W_edge[k * 128 + c]); return; }
    i -= 128 * 128;
    if (i < 128 * 128) { int c = i >> 7, k = i & 127;
        WTm[c * 128 + k] = f2bfs(W_msg[k * 128 + c]); return; }
    i -= 128 * 128;
    if (i < NB * HH) g[i] = 0.f;
}

// S[v][h] = sum of mem over v's (contiguous) out-edge segment
__global__ void node_sum_kernel(const unsigned short* __restrict__ mem,
                                const int* __restrict__ ptr, float* __restrict__ S) {
    int v = blockIdx.x, h = threadIdx.x;
    int s = ptr[v], e1 = ptr[v + 1];
    float acc = 0.f;
    for (int e = s; e < e1; ++e) acc += bfs2f(mem[(size_t)e * HH + h]);
    S[(size_t)v * HH + h] = acc;
}

// ---------- fused embed+edge GEMM: t = tanh(cat@W_emb+b_emb); ef2 = t@W_edge+b_prop;
//            mem1 = tanh(ef2)  (MP iter 1, since mem0 == 0) ----------
__global__ __launch_bounds__(256) void g01_kernel(
    const float* __restrict__ nodes, const float* __restrict__ edgesF,
    const unsigned short* __restrict__ WTe, const unsigned short* __restrict__ WTd,
    const float* __restrict__ b_emb, const float* __restrict__ b_prop,
    const int* __restrict__ bI, const int* __restrict__ nI, const int* __restrict__ nhI,
    float* __restrict__ ef2, unsigned short* __restrict__ mem1, int E)
{
    __shared__ __align__(16) char lds[51200];
    unsigned short* A = (unsigned short*)lds;          // [64][168] bf16 (K=160 padded)
    const int tid = threadIdx.x;
    const int e0  = blockIdx.x * 64;

    // stage cat rows -> bf16 LDS (zeros for pad / tail)
    for (int s = tid; s < 1280; s += 256) {            // 64 rows * 20 k-groups
        int row = s / 20, kg = s % 20, k0 = kg * 8;
        int e = e0 + row;
        float f0=0,f1=0,f2=0,f3=0,f4=0,f5=0,f6=0,f7=0;
        if (e < E && k0 < 144) {
            int b = bI[e], n = nI[e], nh = nhI[e];
            const float* p;
            if (k0 < 64)        p = nodes  + ((((size_t)b << 6) + n)  << 6) + k0;
            else if (k0 < 128)  p = nodes  + ((((size_t)b << 6) + nh) << 6) + (k0 - 64);
            else                p = edgesF + ((((((size_t)b << 6) + n) << 6) + nh) << 4) + (k0 - 128);
            float4 x = *(const float4*)p, y = *(const float4*)(p + 4);
            f0=x.x; f1=x.y; f2=x.z; f3=x.w; f4=y.x; f5=y.y; f6=y.z; f7=y.w;
        }
        int4 w;
        w.x = pack2(f2bfs(f0), f2bfs(f1)); w.y = pack2(f2bfs(f2), f2bfs(f3));
        w.z = pack2(f2bfs(f4), f2bfs(f5)); w.w = pack2(f2bfs(f6), f2bfs(f7));
        *(int4*)&A[row * 168 + k0] = w;
    }
    __syncthreads();

    const int lane = tid & 63, wid = tid >> 6;
    const int wm = wid & 1, wn = wid >> 1;
    const int l15 = lane & 15, lk = lane >> 4;
    const int r0 = wm * 32, cb = wn * 64;

    f32x4 acc[2][4];
    #pragma unroll
    for (int mi = 0; mi < 2; ++mi)
        #pragma unroll
        for (int ni = 0; ni < 4; ++ni) acc[mi][ni] = (f32x4)0.f;

    #pragma unroll
    for (int ks = 0; ks < 5; ++ks) {                  // K=160
        bf16x8 a0 = *(const bf16x8*)&A[(r0 + l15)      * 168 + ks * 32 + lk * 8];
        bf16x8 a1 = *(const bf16x8*)&A[(r0 + 16 + l15) * 168 + ks * 32 + lk * 8];
        #pragma unroll
        for (int ni = 0; ni < 4; ++ni) {
            bf16x8 bb = *(const bf16x8*)&WTe[(size_t)(cb + ni * 16 + l15) * 160 + ks * 32 + lk * 8];
            acc[0][ni] = mfma16(a0, bb, acc[0][ni]);
            acc[1][ni] = mfma16(a1, bb, acc[1][ni]);
        }
    }
    __syncthreads();

    // t -> LDS [64][136] bf16 (C layout: col=lane&15, row=(lane>>4)*4+reg)
    unsigned short* T = (unsigned short*)lds;
    #pragma unroll
    for (int mi = 0; mi < 2; ++mi)
        #pragma unroll
        for (int ni = 0; ni < 4; ++ni) {
            int col = cb + ni * 16 + l15;
            float be = b_emb[col];
            #pragma unroll
            for (int j = 0; j < 4; ++j) {
                int row = r0 + mi * 16 + lk * 4 + j;
                T[row * 136 + col] = f2bfs(tanh_fast(acc[mi][ni][j] + be));
            }
        }
    __syncthreads();

    f32x4 acc2[2][4];
    #pragma unroll
    for (int mi = 0; mi < 2; ++mi)
        #pragma unroll
        for (int ni = 0; ni < 4; ++ni) acc2[mi][ni] = (f32x4)0.f;

    #pragma unroll
    for (int ks = 0; ks < 4; ++ks) {                  // K=128
        bf16x8 a0 = *(const bf16x8*)&T[(r0 + l15)      * 136 + ks * 32 + lk * 8];
        bf16x8 a1 = *(const bf16x8*)&T[(r0 + 16 + l15) * 136 + ks * 32 + lk * 8];
        #pragma unroll
        for (int ni = 0; ni < 4; ++ni) {
            bf16x8 bb = *(const bf16x8*)&WTd[(size_t)(cb + ni * 16 + l15) * 128 + ks * 32 + lk * 8];
            acc2[0][ni] = mfma16(a0, bb, acc2[0][ni]);
            acc2[1][ni] = mfma16(a1, bb, acc2[1][ni]);
        }
    }
    __syncthreads();

    // epilogue bounce: ef2 (f32) + mem1 (bf16), then coalesced stores
    float*          EF = (float*)lds;                          // [64][132]
    unsigned short* MB = (unsigned short*)(lds + 64 * 132 * 4); // [64][136]
    #pragma unroll
    for (int mi = 0; mi < 2; ++mi)
        #pragma unroll
        for (int ni = 0; ni < 4; ++ni) {
            int col = cb + ni * 16 + l15;
            float bp = b_prop[col];
            #pragma unroll
            for (int j = 0; j < 4; ++j) {
                int row = r0 + mi * 16 + lk * 4 + j;
                float z = acc2[mi][ni][j] + bp;
                EF[row * 132 + col] = z;
                MB[row * 136 + col] = f2bfs(tanh_fast(z));
            }
        }
    __syncthreads();
    for (int s = tid; s < 2048; s += 256) {
        int row = s >> 5, c0 = (s & 31) * 4, e = e0 + row;
        if (e < E) *(float4*)&ef2[(size_t)e * HH + c0] = *(const float4*)&EF[row * 132 + c0];
    }
    for (int s = tid; s < 1024; s += 256) {
        int row = s >> 4, c0 = (s & 15) * 8, e = e0 + row;
        if (e < E) *(int4*)&mem1[(size_t)e * HH + c0] = *(const int4*)&MB[row * 136 + c0];
    }
}

// ---------- MP iteration GEMM: mem' = tanh((S[b,nhb]-mem[rev]) @ W_msg + ef2)
//            LAST: instead of storing mem', atomicAdd into g[b][:] ----------
template <int LAST>
__global__ __launch_bounds__(256) void gmsg_kernel(
    const unsigned short* __restrict__ memIn, const float* __restrict__ S,
    const float* __restrict__ ef2, const unsigned short* __restrict__ WTm,
    const int* __restrict__ rev, const int* __restrict__ segnh,
    unsigned short* __restrict__ memOut, float* __restrict__ g, int E)
{
    __shared__ __align__(16) char lds[17408];
    unsigned short* A = (unsigned short*)lds;          // [64][136]
    const int tid = threadIdx.x;
    const int e0  = blockIdx.x * 64;

    for (int s = tid; s < 1024; s += 256) {            // 64 rows * 16 k-groups
        int row = s >> 4, k0 = (s & 15) * 8;
        int e = e0 + row;
        int4 w;
        if (e < E) {
            int sg = segnh[e], rv = rev[e];
            const float* sp = &S[(size_t)sg * HH + k0];
            float4 s0 = *(const float4*)sp, s1 = *(const float4*)(sp + 4);
            int4 mraw = *(const int4*)&memIn[(size_t)rv * HH + k0];
            float m0 = bfs2f((unsigned short)(mraw.x & 0xFFFF)), m1 = bfs2f((unsigned short)((unsigned)mraw.x >> 16));
            float m2 = bfs2f((unsigned short)(mraw.y & 0xFFFF)), m3 = bfs2f((unsigned short)((unsigned)mraw.y >> 16));
            float m4 = bfs2f((unsigned short)(mraw.z & 0xFFFF)), m5 = bfs2f((unsigned short)((unsigned)mraw.z >> 16));
            float m6 = bfs2f((unsigned short)(mraw.w & 0xFFFF)), m7 = bfs2f((unsigned short)((unsigned)mraw.w >> 16));
            w.x = pack2(f2bfs(s0.x - m0), f2bfs(s0.y - m1));
            w.y = pack2(f2bfs(s0.z - m2), f2bfs(s0.w - m3));
            w.z = pack2(f2bfs(s1.x - m4), f2bfs(s1.y - m5));
            w.w = pack2(f2bfs(s1.z - m6), f2bfs(s1.w - m7));
        } else { w.x = w.y = w.z = w.w = 0; }
        *(int4*)&A[row * 136 + k0] = w;
    }
    __syncthreads();

    const int lane = tid & 63, wid = tid >> 6;
    const int wm = wid & 1, wn = wid >> 1;
    const int l15 = lane & 15, lk = lane >> 4;
    const int r0 = wm * 32, cb = wn * 64;

    f32x4 acc[2][4];
    #pragma unroll
    for (int mi = 0; mi < 2; ++mi)
        #pragma unroll
        for (int ni = 0; ni < 4; ++ni) acc[mi][ni] = (f32x4)0.f;

    #pragma unroll
    for (int ks = 0; ks < 4; ++ks) {
        bf16x8 a0 = *(const bf16x8*)&A[(r0 + l15)      * 136 + ks * 32 + lk * 8];
        bf16x8 a1 = *(const bf16x8*)&A[(r0 + 16 + l15) * 136 + ks * 32 + lk * 8];
        #pragma unroll
        for (int ni = 0; ni < 4; ++ni) {
            bf16x8 bb = *(const bf16x8*)&WTm[(size_t)(cb + ni * 16 + l15) * 128 + ks * 32 + lk * 8];
            acc[0][ni] = mfma16(a0, bb, acc[0][ni]);
            acc[1][ni] = mfma16(a1, bb, acc[1][ni]);
        }
    }

    if (LAST) {
        #pragma unroll
        for (int mi = 0; mi < 2; ++mi)
            #pragma unroll
            for (int ni = 0; ni < 4; ++ni) {
                int col = cb + ni * 16 + l15;
                #pragma unroll
                for (int j = 0; j < 4; ++j) {
                    int row = r0 + mi * 16 + lk * 4 + j;
                    int e = e0 + row;
                    if (e < E) {
                        float z = acc[mi][ni][j] + ef2[(size_t)e * HH + col];
                        int b = segnh[e] >> 6;
                        atomicAdd(&g[(size_t)b * HH + col], tanh_fast(z));
                    }
                }
            }
    } else {
        __syncthreads();
        unsigned short* MB = A;                        // reuse [64][136]
        #pragma unroll
        for (int mi = 0; mi < 2; ++mi)
            #pragma unroll
            for (int ni = 0; ni < 4; ++ni) {
                int col = cb + ni * 16 + l15;
                #pragma unroll
                for (int j = 0; j < 4; ++j) {
                    int row = r0 + mi * 16 + lk * 4 + j;
                    int e = e0 + row;
                    float ez = (e < E) ? ef2[(size_t)e * HH + col] : 0.f;
                    MB[row * 136 + col] = f2bfs(tanh_fast(acc[mi][ni][j] + ez));
                }
            }
        __syncthreads();
        for (int s = tid; s < 1024; s += 256) {
            int row = s >> 4, c0 = (s & 15) * 8, e = e0 + row;
            if (e < E) *(int4*)&memOut[(size_t)e * HH + c0] = *(const int4*)&MB[row * 136 + c0];
        }
    }
}

// out[b] = g[b] @ W_out + b_out
__global__ void out2_kernel(const float* __restrict__ g, const float* __restrict__ W_out,
                            const float* __restrict__ b_out, float* __restrict__ out) {
    int b = blockIdx.x, tid = threadIdx.x;
    if (tid < 32) {
        float a = b_out[tid];
        for (int h = 0; h < HH; ++h) a += g[(size_t)b * HH + h] * W_out[h * 32 + tid];
        out[b * 32 + tid] = a;
    }
}

extern "C" void kernel_launch(void* const* d_in, const int* in_sizes, int n_in,
                              void* d_out, int out_size, void* d_ws, size_t ws_size,
                              hipStream_t stream) {
    const float* nodes  = (const float*)d_in[0];
    const float* edgesF = (const float*)d_in[1];
    const float* W_emb  = (const float*)d_in[2];
    const float* b_emb  = (const float*)d_in[3];
    const float* W_msg  = (const float*)d_in[4];
    const float* W_edge = (const float*)d_in[5];
    const float* b_prop = (const float*)d_in[6];
    const float* W_out  = (const float*)d_in[7];
    const float* b_out  = (const float*)d_in[8];
    const int*   bI     = (const int*)d_in[9];
    const int*   nI     = (const int*)d_in[10];
    const int*   nhI    = (const int*)d_in[11];
    const int    E      = in_sizes[9];
    float*       out    = (float*)d_out;

    char* ws = (char*)d_ws;
    size_t al = 255;
    size_t szEf  = (((size_t)E * HH * 4) + al) & ~al;
    size_t szMem = (((size_t)E * HH * 2) + al) & ~al;
    size_t szI   = (((size_t)E * 4) + al) & ~al;
    float*          ef2   = (float*)ws;                      ws += szEf;
    unsigned short* memA  = (unsigned short*)ws;             ws += szMem;
    unsigned short* memB  = (unsigned short*)ws;             ws += szMem;
    float*          S     = (float*)ws;                      ws += (size_t)NB * NN * HH * 4;
    float*          g     = (float*)ws;                      ws += (size_t)NB * HH * 4;
    int*            idmat = (int*)ws;                        ws += (size_t)NB * NN * NN * 4;
    int*            rev   = (int*)ws;                        ws += szI;
    int*            segnh = (int*)ws;                        ws += szI;
    int*            ptr   = (int*)ws;                        ws += (((size_t)(NB * NN + 1) * 4) + al) & ~al;
    unsigned short* WTe   = (unsigned short*)ws;             ws += 128 * 160 * 2;
    unsigned short* WTd   = (unsigned short*)ws;             ws += 128 * 128 * 2;
    unsigned short* WTm   = (unsigned short*)ws;             ws += 128 * 128 * 2;

    scatter_ids_kernel  <<<cdiv(E, 256), 256, 0, stream>>>(bI, nI, nhI, idmat, E);
    build_rev_seg_kernel<<<cdiv(E, 256), 256, 0, stream>>>(bI, nI, nhI, idmat, rev, segnh, E);
    build_ptr_kernel    <<<cdiv(NB * NN + 1, 256), 256, 0, stream>>>(bI, nI, E, ptr);
    prep_w_kernel       <<<cdiv(128 * 160 + 2 * 128 * 128 + NB * HH, 256), 256, 0, stream>>>(
                          W_emb, W_edge, W_msg, WTe, WTd, WTm, g);

    const int gb = cdiv(E, 64);
    g01_kernel<<<gb, 256, 0, stream>>>(nodes, edgesF, WTe, WTd, b_emb, b_prop,
                                       bI, nI, nhI, ef2, memA, E);
    // MP iters 2..4
    node_sum_kernel<<<NB * NN, HH, 0, stream>>>(memA, ptr, S);
    gmsg_kernel<0><<<gb, 256, 0, stream>>>(memA, S, ef2, WTm, rev, segnh, memB, g, E);
    node_sum_kernel<<<NB * NN, HH, 0, stream>>>(memB, ptr, S);
    gmsg_kernel<0><<<gb, 256, 0, stream>>>(memB, S, ef2, WTm, rev, segnh, memA, g, E);
    node_sum_kernel<<<NB * NN, HH, 0, stream>>>(memA, ptr, S);
    gmsg_kernel<1><<<gb, 256, 0, stream>>>(memA, S, ef2, WTm, rev, segnh, nullptr, g, E);

    out2_kernel<<<NB, 64, 0, stream>>>(g, W_out, b_out, out);
}

// Round 4
// 286.868 us; speedup vs baseline: 1.5048x; 1.1937x over previous
//
#include <hip/hip_runtime.h>
#include <hip/hip_bf16.h>

#define NB 128
#define NN 64
#define HH 128

typedef short bf16x8 __attribute__((ext_vector_type(8)));
typedef float f32x4 __attribute__((ext_vector_type(4)));

static inline int cdiv(int a, int b) { return (a + b - 1) / b; }

__device__ __forceinline__ float tanh_fast(float x) {
    float ax = fabsf(x);
    float ex = __expf(-2.0f * ax);
    float t  = (1.0f - ex) / (1.0f + ex);
    return copysignf(t, x);
}

// RNE float->bf16 (raw ushort) and back
__device__ __forceinline__ unsigned short f2bfs(float f) {
    unsigned u; __builtin_memcpy(&u, &f, 4);
    u = (u + 0x7FFFu + ((u >> 16) & 1u)) >> 16;
    return (unsigned short)u;
}
__device__ __forceinline__ float bfs2f(unsigned short s) {
    unsigned u = ((unsigned)s) << 16;
    float f; __builtin_memcpy(&f, &u, 4);
    return f;
}
__device__ __forceinline__ int pack2(unsigned short a, unsigned short b) {
    return (int)((unsigned)a | ((unsigned)b << 16));
}
__device__ __forceinline__ f32x4 mfma16(bf16x8 a, bf16x8 b, f32x4 c) {
    return __builtin_amdgcn_mfma_f32_16x16x32_bf16(a, b, c, 0, 0, 0);
}

// ---------- graph index prep ----------
__global__ void scatter_ids_kernel(const int* __restrict__ bI, const int* __restrict__ nI,
                                   const int* __restrict__ nhI, int* __restrict__ idmat, int E) {
    int e = blockIdx.x * blockDim.x + threadIdx.x;
    if (e >= E) return;
    idmat[((bI[e] << 6) + nI[e]) * NN + nhI[e]] = e;
}
// rev[e] = id of reverse edge (exists: A symmetric)
__global__ void build_rev_kernel(const int* __restrict__ bI, const int* __restrict__ nI,
                                 const int* __restrict__ nhI, const int* __restrict__ idmat,
                                 int* __restrict__ rev, int E) {
    int e = blockIdx.x * blockDim.x + threadIdx.x;
    if (e >= E) return;
    rev[e] = idmat[((bI[e] << 6) + nhI[e]) * NN + nI[e]];
}
// node_ptr[v] = lower_bound of seg(e)=b*64+n (edges sorted by (b,n,nhb))
__global__ void build_ptr_kernel(const int* __restrict__ bI, const int* __restrict__ nI,
                                 int E, int* __restrict__ ptr) {
    int v = blockIdx.x * blockDim.x + threadIdx.x;
    if (v > NB * NN) return;
    int lo = 0, hi = E;
    while (lo < hi) {
        int mid = (lo + hi) >> 1;
        int sg = (bI[mid] << 6) + nI[mid];
        if (sg < v) lo = mid + 1; else hi = mid;
    }
    ptr[v] = lo;
}
// transpose weights to bf16 WT[col][k]; K of W_emb zero-padded 144->160; zero g
__global__ void prep_w_kernel(const float* __restrict__ W_emb, const float* __restrict__ W_edge,
                              const float* __restrict__ W_msg,
                              unsigned short* __restrict__ WTe, unsigned short* __restrict__ WTd,
                              unsigned short* __restrict__ WTm, float* __restrict__ g) {
    int i = blockIdx.x * blockDim.x + threadIdx.x;
    if (i < 128 * 160) { int c = i / 160, k = i % 160;
        WTe[c * 160 + k] = f2bfs(k < 144 ? W_emb[k * 128 + c] : 0.f); return; }
    i -= 128 * 160;
    if (i < 128 * 128) { int c = i >> 7, k = i & 127;
        WTd[c * 128 + k] = f2bfs(W_edge[k * 128 + c]); return; }
    i -= 128 * 128;
    if (i < 128 * 128) { int c = i >> 7, k = i & 127;
        WTm[c * 128 + k] = f2bfs(W_msg[k * 128 + c]); return; }
    i -= 128 * 128;
    if (i < NB * HH) g[i] = 0.f;
}

// ---------- fused embed+edge GEMM: t = tanh(cat@W_emb+b_emb); ef2 = t@W_edge+b_prop;
//            mem1 = tanh(ef2)  (MP iter 1, since mem0 == 0) ----------
__global__ __launch_bounds__(256) void g01_kernel(
    const float* __restrict__ nodes, const float* __restrict__ edgesF,
    const unsigned short* __restrict__ WTe, const unsigned short* __restrict__ WTd,
    const float* __restrict__ b_emb, const float* __restrict__ b_prop,
    const int* __restrict__ bI, const int* __restrict__ nI, const int* __restrict__ nhI,
    float* __restrict__ ef2, unsigned short* __restrict__ mem1, int E)
{
    __shared__ __align__(16) char lds[51200];
    unsigned short* A = (unsigned short*)lds;          // [64][168] bf16 (K=160 padded)
    const int tid = threadIdx.x;
    const int e0  = blockIdx.x * 64;

    for (int s = tid; s < 1280; s += 256) {            // 64 rows * 20 k-groups
        int row = s / 20, kg = s % 20, k0 = kg * 8;
        int e = e0 + row;
        float f0=0,f1=0,f2=0,f3=0,f4=0,f5=0,f6=0,f7=0;
        if (e < E && k0 < 144) {
            int b = bI[e], n = nI[e], nh = nhI[e];
            const float* p;
            if (k0 < 64)        p = nodes  + ((((size_t)b << 6) + n)  << 6) + k0;
            else if (k0 < 128)  p = nodes  + ((((size_t)b << 6) + nh) << 6) + (k0 - 64);
            else                p = edgesF + ((((((size_t)b << 6) + n) << 6) + nh) << 4) + (k0 - 128);
            float4 x = *(const float4*)p, y = *(const float4*)(p + 4);
            f0=x.x; f1=x.y; f2=x.z; f3=x.w; f4=y.x; f5=y.y; f6=y.z; f7=y.w;
        }
        int4 w;
        w.x = pack2(f2bfs(f0), f2bfs(f1)); w.y = pack2(f2bfs(f2), f2bfs(f3));
        w.z = pack2(f2bfs(f4), f2bfs(f5)); w.w = pack2(f2bfs(f6), f2bfs(f7));
        *(int4*)&A[row * 168 + k0] = w;
    }
    __syncthreads();

    const int lane = tid & 63, wid = tid >> 6;
    const int wm = wid & 1, wn = wid >> 1;
    const int l15 = lane & 15, lk = lane >> 4;
    const int r0 = wm * 32, cb = wn * 64;

    f32x4 acc[2][4];
    #pragma unroll
    for (int mi = 0; mi < 2; ++mi)
        #pragma unroll
        for (int ni = 0; ni < 4; ++ni) acc[mi][ni] = (f32x4)0.f;

    #pragma unroll
    for (int ks = 0; ks < 5; ++ks) {                  // K=160
        bf16x8 a0 = *(const bf16x8*)&A[(r0 + l15)      * 168 + ks * 32 + lk * 8];
        bf16x8 a1 = *(const bf16x8*)&A[(r0 + 16 + l15) * 168 + ks * 32 + lk * 8];
        #pragma unroll
        for (int ni = 0; ni < 4; ++ni) {
            bf16x8 bb = *(const bf16x8*)&WTe[(size_t)(cb + ni * 16 + l15) * 160 + ks * 32 + lk * 8];
            acc[0][ni] = mfma16(a0, bb, acc[0][ni]);
            acc[1][ni] = mfma16(a1, bb, acc[1][ni]);
        }
    }
    __syncthreads();

    unsigned short* T = (unsigned short*)lds;          // t [64][136] bf16
    #pragma unroll
    for (int mi = 0; mi < 2; ++mi)
        #pragma unroll
        for (int ni = 0; ni < 4; ++ni) {
            int col = cb + ni * 16 + l15;
            float be = b_emb[col];
            #pragma unroll
            for (int j = 0; j < 4; ++j) {
                int row = r0 + mi * 16 + lk * 4 + j;
                T[row * 136 + col] = f2bfs(tanh_fast(acc[mi][ni][j] + be));
            }
        }
    __syncthreads();

    f32x4 acc2[2][4];
    #pragma unroll
    for (int mi = 0; mi < 2; ++mi)
        #pragma unroll
        for (int ni = 0; ni < 4; ++ni) acc2[mi][ni] = (f32x4)0.f;

    #pragma unroll
    for (int ks = 0; ks < 4; ++ks) {                  // K=128
        bf16x8 a0 = *(const bf16x8*)&T[(r0 + l15)      * 136 + ks * 32 + lk * 8];
        bf16x8 a1 = *(const bf16x8*)&T[(r0 + 16 + l15) * 136 + ks * 32 + lk * 8];
        #pragma unroll
        for (int ni = 0; ni < 4; ++ni) {
            bf16x8 bb = *(const bf16x8*)&WTd[(size_t)(cb + ni * 16 + l15) * 128 + ks * 32 + lk * 8];
            acc2[0][ni] = mfma16(a0, bb, acc2[0][ni]);
            acc2[1][ni] = mfma16(a1, bb, acc2[1][ni]);
        }
    }
    __syncthreads();

    float*          EF = (float*)lds;                           // [64][132]
    unsigned short* MB = (unsigned short*)(lds + 64 * 132 * 4); // [64][136]
    #pragma unroll
    for (int mi = 0; mi < 2; ++mi)
        #pragma unroll
        for (int ni = 0; ni < 4; ++ni) {
            int col = cb + ni * 16 + l15;
            float bp = b_prop[col];
            #pragma unroll
            for (int j = 0; j < 4; ++j) {
                int row = r0 + mi * 16 + lk * 4 + j;
                float z = acc2[mi][ni][j] + bp;
                EF[row * 132 + col] = z;
                MB[row * 136 + col] = f2bfs(tanh_fast(z));
            }
        }
    __syncthreads();
    for (int s = tid; s < 2048; s += 256) {
        int row = s >> 5, c0 = (s & 31) * 4, e = e0 + row;
        if (e < E) *(float4*)&ef2[(size_t)e * HH + c0] = *(const float4*)&EF[row * 132 + c0];
    }
    for (int s = tid; s < 1024; s += 256) {
        int row = s >> 4, c0 = (s & 15) * 8, e = e0 + row;
        if (e < E) *(int4*)&mem1[(size_t)e * HH + c0] = *(const int4*)&MB[row * 136 + c0];
    }
}

// ---------- fused MP iteration, node-centric. Block = node u (1 wave).
// For f in out(u) (contiguous rows): the edges e with nh(e)=u are exactly rev(f),
// and msg[rev(f)] = S[u] - mem[f] with S[u] = sum of the same contiguous rows.
// mem'[rev(f)] = tanh(msg @ W_msg + ef2[rev(f)]).   LAST: atomicAdd tanh rows into g[b].
template <int LAST>
__global__ __launch_bounds__(64) void mp_kernel(
    const unsigned short* __restrict__ memIn, const float* __restrict__ ef2,
    const unsigned short* __restrict__ WTm, const int* __restrict__ rev,
    const int* __restrict__ ptr, unsigned short* __restrict__ memOut,
    float* __restrict__ g)
{
    const int u = blockIdx.x;
    const int s = ptr[u], e1 = ptr[u + 1];
    const int deg = e1 - s;
    if (deg == 0) return;

    __shared__ __align__(16) char ldsu[16 * 132 * 4];   // union: A[16][136] bf16 / C[16][132] f32
    __shared__ float Srow[128];
    __shared__ int   rvls[16];
    unsigned short* A = (unsigned short*)ldsu;
    float*          C = (float*)ldsu;

    const int lane = threadIdx.x;
    const int l15 = lane & 15, lk = lane >> 4;

    // stage chunk-0 mem rows (bf16 raw), zero-pad
    {
        const int m0 = min(deg, 16);
        #pragma unroll
        for (int ii = 0; ii < 4; ++ii) {
            int sl = lane + ii * 64;
            int r = sl >> 4, k0 = (sl & 15) * 8;
            int4 w = make_int4(0, 0, 0, 0);
            if (r < m0) w = *(const int4*)&memIn[(size_t)(s + r) * HH + k0];
            *(int4*)&A[r * 136 + k0] = w;
        }
    }
    __syncthreads();

    // S[u] column sums (2 cols/lane): chunk-0 rows from LDS, tail rows from global
    {
        float s0 = 0.f, s1 = 0.f;
        const int m0 = min(deg, 16);
        for (int r = 0; r < m0; ++r) {
            s0 += bfs2f(A[r * 136 + lane]);
            s1 += bfs2f(A[r * 136 + lane + 64]);
        }
        for (int r = 16; r < deg; ++r) {
            s0 += bfs2f(memIn[(size_t)(s + r) * HH + lane]);
            s1 += bfs2f(memIn[(size_t)(s + r) * HH + lane + 64]);
        }
        Srow[lane] = s0; Srow[lane + 64] = s1;
    }

    float ga0 = 0.f, ga1 = 0.f;     // LAST accumulators

    for (int c0 = 0; c0 < deg; c0 += 16) {
        const int nrows = min(16, deg - c0);
        if (c0) {
            __syncthreads();        // prior epilogue done with LDS
            #pragma unroll
            for (int ii = 0; ii < 4; ++ii) {
                int sl = lane + ii * 64;
                int r = sl >> 4, k0 = (sl & 15) * 8;
                int4 w = make_int4(0, 0, 0, 0);
                if (r < nrows) w = *(const int4*)&memIn[(size_t)(s + c0 + r) * HH + k0];
                *(int4*)&A[r * 136 + k0] = w;
            }
        }
        if (lane < nrows) rvls[lane] = rev[s + c0 + lane];
        __syncthreads();            // stage + rvls + (chunk0) Srow visible

        // in-place: A[r][k] = bf16(S[k] - mem_row[r][k])  (pad rows become S, discarded later)
        #pragma unroll
        for (int ii = 0; ii < 4; ++ii) {
            int sl = lane + ii * 64;
            int r = sl >> 4, k0 = (sl & 15) * 8;
            int4 w = *(const int4*)&A[r * 136 + k0];
            unsigned short hs[8];
            #pragma unroll
            for (int q = 0; q < 4; ++q) {
                int raw = (&w.x)[q];
                float lo = bfs2f((unsigned short)(raw & 0xFFFF));
                float hi = bfs2f((unsigned short)((unsigned)raw >> 16));
                hs[2 * q]     = f2bfs(Srow[k0 + 2 * q]     - lo);
                hs[2 * q + 1] = f2bfs(Srow[k0 + 2 * q + 1] - hi);
            }
            int4 o;
            o.x = pack2(hs[0], hs[1]); o.y = pack2(hs[2], hs[3]);
            o.z = pack2(hs[4], hs[5]); o.w = pack2(hs[6], hs[7]);
            *(int4*)&A[r * 136 + k0] = o;
        }
        __syncthreads();

        // 16x128 @ 128x128 MFMA (B from global WTm, L1-hot: 32 KB)
        f32x4 acc[8];
        #pragma unroll
        for (int ni = 0; ni < 8; ++ni) acc[ni] = (f32x4)0.f;
        #pragma unroll
        for (int ks = 0; ks < 4; ++ks) {
            bf16x8 a = *(const bf16x8*)&A[l15 * 136 + ks * 32 + lk * 8];
            #pragma unroll
            for (int ni = 0; ni < 8; ++ni) {
                bf16x8 bb = *(const bf16x8*)&WTm[(size_t)(ni * 16 + l15) * HH + ks * 32 + lk * 8];
                acc[ni] = mfma16(a, bb, acc[ni]);
            }
        }
        __syncthreads();            // A dead; reuse as C

        #pragma unroll
        for (int ni = 0; ni < 8; ++ni)
            #pragma unroll
            for (int j = 0; j < 4; ++j)
                C[(lk * 4 + j) * 132 + ni * 16 + l15] = acc[ni][j];
        __syncthreads();

        if (!LAST) {
            #pragma unroll
            for (int ii = 0; ii < 4; ++ii) {
                int sl = lane + ii * 64;
                int r = sl >> 4, k0 = (sl & 15) * 8;
                if (r < nrows) {
                    int rv = rvls[r];
                    const float* ep = &ef2[(size_t)rv * HH + k0];
                    float4 f0 = *(const float4*)ep, f1 = *(const float4*)(ep + 4);
                    const float* cp = &C[r * 132 + k0];
                    unsigned short hs[8];
                    hs[0] = f2bfs(tanh_fast(cp[0] + f0.x)); hs[1] = f2bfs(tanh_fast(cp[1] + f0.y));
                    hs[2] = f2bfs(tanh_fast(cp[2] + f0.z)); hs[3] = f2bfs(tanh_fast(cp[3] + f0.w));
                    hs[4] = f2bfs(tanh_fast(cp[4] + f1.x)); hs[5] = f2bfs(tanh_fast(cp[5] + f1.y));
                    hs[6] = f2bfs(tanh_fast(cp[6] + f1.z)); hs[7] = f2bfs(tanh_fast(cp[7] + f1.w));
                    int4 o;
                    o.x = pack2(hs[0], hs[1]); o.y = pack2(hs[2], hs[3]);
                    o.z = pack2(hs[4], hs[5]); o.w = pack2(hs[6], hs[7]);
                    *(int4*)&memOut[(size_t)rv * HH + k0] = o;
                }
            }
        } else {
            for (int r = 0; r < nrows; ++r) {
                int rv = rvls[r];
                ga0 += tanh_fast(C[r * 132 + lane]      + ef2[(size_t)rv * HH + lane]);
                ga1 += tanh_fast(C[r * 132 + lane + 64] + ef2[(size_t)rv * HH + lane + 64]);
            }
        }
    }

    if (LAST) {
        const int b = u >> 6;
        atomicAdd(&g[(size_t)b * HH + lane],      ga0);
        atomicAdd(&g[(size_t)b * HH + lane + 64], ga1);
    }
}

// out[b] = g[b] @ W_out + b_out
__global__ void out2_kernel(const float* __restrict__ g, const float* __restrict__ W_out,
                            const float* __restrict__ b_out, float* __restrict__ out) {
    int b = blockIdx.x, tid = threadIdx.x;
    if (tid < 32) {
        float a = b_out[tid];
        for (int h = 0; h < HH; ++h) a += g[(size_t)b * HH + h] * W_out[h * 32 + tid];
        out[b * 32 + tid] = a;
    }
}

extern "C" void kernel_launch(void* const* d_in, const int* in_sizes, int n_in,
                              void* d_out, int out_size, void* d_ws, size_t ws_size,
                              hipStream_t stream) {
    const float* nodes  = (const float*)d_in[0];
    const float* edgesF = (const float*)d_in[1];
    const float* W_emb  = (const float*)d_in[2];
    const float* b_emb  = (const float*)d_in[3];
    const float* W_msg  = (const float*)d_in[4];
    const float* W_edge = (const float*)d_in[5];
    const float* b_prop = (const float*)d_in[6];
    const float* W_out  = (const float*)d_in[7];
    const float* b_out  = (const float*)d_in[8];
    const int*   bI     = (const int*)d_in[9];
    const int*   nI     = (const int*)d_in[10];
    const int*   nhI    = (const int*)d_in[11];
    const int    E      = in_sizes[9];
    float*       out    = (float*)d_out;

    char* ws = (char*)d_ws;
    size_t al = 255;
    size_t szEf  = (((size_t)E * HH * 4) + al) & ~al;
    size_t szMem = (((size_t)E * HH * 2) + al) & ~al;
    size_t szI   = (((size_t)E * 4) + al) & ~al;
    float*          ef2   = (float*)ws;                      ws += szEf;
    unsigned short* memA  = (unsigned short*)ws;             ws += szMem;
    unsigned short* memB  = (unsigned short*)ws;             ws += szMem;
    float*          g     = (float*)ws;                      ws += (size_t)NB * HH * 4;
    int*            idmat = (int*)ws;                        ws += (size_t)NB * NN * NN * 4;
    int*            rev   = (int*)ws;                        ws += szI;
    int*            ptr   = (int*)ws;                        ws += (((size_t)(NB * NN + 1) * 4) + al) & ~al;
    unsigned short* WTe   = (unsigned short*)ws;             ws += 128 * 160 * 2;
    unsigned short* WTd   = (unsigned short*)ws;             ws += 128 * 128 * 2;
    unsigned short* WTm   = (unsigned short*)ws;             ws += 128 * 128 * 2;

    scatter_ids_kernel<<<cdiv(E, 256), 256, 0, stream>>>(bI, nI, nhI, idmat, E);
    build_rev_kernel  <<<cdiv(E, 256), 256, 0, stream>>>(bI, nI, nhI, idmat, rev, E);
    build_ptr_kernel  <<<cdiv(NB * NN + 1, 256), 256, 0, stream>>>(bI, nI, E, ptr);
    prep_w_kernel     <<<cdiv(128 * 160 + 2 * 128 * 128 + NB * HH, 256), 256, 0, stream>>>(
                        W_emb, W_edge, W_msg, WTe, WTd, WTm, g);

    const int gb = cdiv(E, 64);
    g01_kernel<<<gb, 256, 0, stream>>>(nodes, edgesF, WTe, WTd, b_emb, b_prop,
                                       bI, nI, nhI, ef2, memA, E);
    // MP iters 2..4 (fused node-sum + edge GEMM, node-centric)
    mp_kernel<0><<<NB * NN, 64, 0, stream>>>(memA, ef2, WTm, rev, ptr, memB, nullptr);
    mp_kernel<0><<<NB * NN, 64, 0, stream>>>(memB, ef2, WTm, rev, ptr, memA, nullptr);
    mp_kernel<1><<<NB * NN, 64, 0, stream>>>(memA, ef2, WTm, rev, ptr, nullptr, g);

    out2_kernel<<<NB, 64, 0, stream>>>(g, W_out, b_out, out);
}